// Round 8
// baseline (1468.526 us; speedup 1.0000x reference)
//
#include <hip/hip_runtime.h>

// R8 — COUNTER-SURFACING ROUND. R7's 4x sweeps (~312us) still lost to the
// 320-325us harness fills in top-5. 6x sweeps (~470-520us) force all three
// dispatches into top-5 so we finally read WRITE_SIZE/FETCH_SIZE/hbm_gbps/
// VALUBusy/Occupancy for: store-only probe, no-LDS compute, R1 compute.
// relpos6x runs LAST and every sweep writes correct data -> output correct.

typedef float f4 __attribute__((ext_vector_type(4)));

constexpr int ROWS = 136;
constexpr int THREADS = 512;
constexpr int GRID = 1024;
constexpr int SWEEPS = 6;

// ---- A: store-only, exact R1 mapping, 6 sweeps (value differs per sweep) ----
__global__ __launch_bounds__(512)
void probe_same6x(f4* __restrict__ out)
{
    const int t = blockIdx.x * 512 + threadIdx.x;
    for (int s = 0; s < SWEEPS; ++s) {
        const float fv = (float)(s + 1);
        const f4 v = {fv, fv, fv, fv};
        size_t o = (size_t)t;
        #pragma unroll 8
        for (int it = 0; it < 64; ++it) {
            out[o] = v;
            o += (size_t)524288;
        }
    }
}

// ---- B: full compute, ZERO LDS (W via L1/L2), no staging, no syncthreads ----
__global__ __launch_bounds__(512)
void relpos_nolds6x(const int* __restrict__ asym,
                    const int* __restrict__ resid,
                    const int* __restrict__ ent,
                    const int* __restrict__ tok,
                    const int* __restrict__ sym,
                    const float* __restrict__ W,
                    f4* __restrict__ outv)
{
    const f4* Wv = reinterpret_cast<const f4*>(W);
    const int t  = blockIdx.x * THREADS + threadIdx.x;
    const int c4 = t & 31;
    const int p0 = t >> 5;
    const int j  = p0 & 1023;
    const int i0 = p0 >> 10;

    const int aj = asym[j];
    const int rj = resid[j];
    const int ej = ent[j];
    const int tj = tok[j];
    const int sj = sym[j];

    const f4 vE = Wv[130 * 32 + c4];

    for (int s = 0; s < SWEEPS; ++s) {
        const int itb = 16 * s;
        #pragma unroll 4
        for (int itc = 0; itc < 64; ++itc) {
            const int it = (itb + itc) & 63;
            const int i  = i0 + 16 * it;

            const int ai = asym[i];
            const int ri = resid[i];
            const int ei = ent[i];
            const int ti = tok[i];
            const int si = sym[i];

            const bool sc = (ai == aj);
            const bool sr = (ri == rj);

            int dres = min(max(rj - ri + 32, 0), 64);
            int dtok = min(max(tj - ti + 32, 0), 64);
            int dch  = min(max(sj - si + 2, 0), 4);
            if (sc)        { dres = 64; dch = 4; }
            if (sc || sr)  { dtok = 64; }
            const float se = (ei == ej) ? 1.0f : 0.0f;

            const f4 v0 = Wv[dres * 32 + c4];
            const f4 v1 = Wv[(65 + dtok) * 32 + c4];
            const f4 v3 = Wv[(131 + dch) * 32 + c4];

            f4 r;
            r.x = fmaf(se, vE.x, v0.x + v1.x) + v3.x;
            r.y = fmaf(se, vE.y, v0.y + v1.y) + v3.y;
            r.z = fmaf(se, vE.z, v0.z + v1.z) + v3.z;
            r.w = fmaf(se, vE.w, v0.w + v1.w) + v3.w;

            outv[(size_t)t + (size_t)it * 524288] = r;
        }
    }
}

// ---- C: exact R1 structure (LDS-staged W), 6 sweeps, runs LAST ----
__global__ __launch_bounds__(THREADS)
void relpos6x(const int* __restrict__ asym,
              const int* __restrict__ resid,
              const int* __restrict__ ent,
              const int* __restrict__ tok,
              const int* __restrict__ sym,
              const float* __restrict__ W,
              f4* __restrict__ outv)
{
    __shared__ f4 sW[ROWS * 32];   // 69,632 B
    const int tid = threadIdx.x;

    const f4* Wv = reinterpret_cast<const f4*>(W);
    for (int k = tid; k < ROWS * 32; k += THREADS)
        sW[k] = Wv[k];
    __syncthreads();

    const int t  = blockIdx.x * THREADS + tid;
    const int c4 = t & 31;
    const int p0 = t >> 5;
    const int j  = p0 & 1023;
    const int i0 = p0 >> 10;

    const int aj = asym[j];
    const int rj = resid[j];
    const int ej = ent[j];
    const int tj = tok[j];
    const int sj = sym[j];

    const f4 vE = sW[130 * 32 + c4];

    for (int s = 0; s < SWEEPS; ++s) {
        const int itb = 16 * s;
        #pragma unroll 4
        for (int itc = 0; itc < 64; ++itc) {
            const int it = (itb + itc) & 63;
            const int i  = i0 + 16 * it;

            const int ai = asym[i];
            const int ri = resid[i];
            const int ei = ent[i];
            const int ti = tok[i];
            const int si = sym[i];

            const bool sc = (ai == aj);
            const bool sr = (ri == rj);

            int dres = min(max(rj - ri + 32, 0), 64);
            int dtok = min(max(tj - ti + 32, 0), 64);
            int dch  = min(max(sj - si + 2, 0), 4);
            if (sc)        { dres = 64; dch = 4; }
            if (sc || sr)  { dtok = 64; }
            const float se = (ei == ej) ? 1.0f : 0.0f;

            const f4 v0 = sW[dres * 32 + c4];
            const f4 v1 = sW[(65 + dtok) * 32 + c4];
            const f4 v3 = sW[(131 + dch) * 32 + c4];

            f4 r;
            r.x = fmaf(se, vE.x, v0.x + v1.x) + v3.x;
            r.y = fmaf(se, vE.y, v0.y + v1.y) + v3.y;
            r.z = fmaf(se, vE.z, v0.z + v1.z) + v3.z;
            r.w = fmaf(se, vE.w, v0.w + v1.w) + v3.w;

            outv[(size_t)t + (size_t)it * 524288] = r;
        }
    }
}

extern "C" void kernel_launch(void* const* d_in, const int* in_sizes, int n_in,
                              void* d_out, int out_size, void* d_ws, size_t ws_size,
                              hipStream_t stream) {
    const int*   asym  = (const int*)  d_in[0];
    const int*   resid = (const int*)  d_in[1];
    const int*   ent   = (const int*)  d_in[2];
    const int*   tok   = (const int*)  d_in[3];
    const int*   sym   = (const int*)  d_in[4];
    const float* W     = (const float*)d_in[5];
    f4* outv = (f4*)d_out;

    probe_same6x  <<<GRID, THREADS, 0, stream>>>(outv);
    relpos_nolds6x<<<GRID, THREADS, 0, stream>>>(asym, resid, ent, tok, sym, W, outv);
    relpos6x      <<<GRID, THREADS, 0, stream>>>(asym, resid, ent, tok, sym, W, outv);
}

// Round 9
// 112.540 us; speedup vs baseline: 13.0489x; 13.0489x over previous
//
#include <hip/hip_runtime.h>

// RelativePositionEncoding — out 512 MiB fp32, HBM-write-bound.
// R9: R1 structure (best of 7) + staging/store overlap.
//   - W->reg staging loads issued immediately (stay in flight)
//   - iterations 0..3 computed with W read straight from global (L1/L3-hot)
//     so the store stream starts ~immediately instead of after 71 MB of
//     LDS staging completes
//   - regs committed to LDS, one __syncthreads, iterations 4..63 from LDS.
// Evidence (R7/R8): steady-state this kernel == store-only probe (~78us/sweep,
// ~6.9 TB/s, WRITE_SIZE fully drains); solo dispatch carries ~48us transient.
// This attacks the code-addressable slice of that transient.

typedef float f4 __attribute__((ext_vector_type(4)));

constexpr int ROWS = 136;      // 65 rel_pos | 65 rel_token | 1 entity | 5 rel_chain
constexpr int THREADS = 512;
constexpr int GRID = 1024;     // 524,288 threads x 64 f4 stores
constexpr int PRIME = 4;       // iterations served from global W before LDS is ready

__global__ __launch_bounds__(THREADS)
void relpos_kernel(const int* __restrict__ asym,
                   const int* __restrict__ resid,
                   const int* __restrict__ ent,
                   const int* __restrict__ tok,
                   const int* __restrict__ sym,
                   const float* __restrict__ W,
                   f4* __restrict__ outv)
{
    __shared__ f4 sW[ROWS * 32];               // 69,632 B
    const int tid = threadIdx.x;
    const f4* Wv = reinterpret_cast<const f4*>(W);   // W as [136*32] f4

    // ---- issue W->reg staging loads NOW; they fly under the prime phase ----
    f4 st[8];                                  // 4096 of 4352 f4
    #pragma unroll
    for (int k = 0; k < 8; ++k)
        st[k] = Wv[tid + k * 512];
    f4 st8;                                    // remaining 256 f4
    if (tid < 256) st8 = Wv[4096 + tid];

    // ---- R1 decomposition: c4 fixed, j fixed, i = i0 + 16*it ----
    const int t  = blockIdx.x * THREADS + tid;
    const int c4 = t & 31;
    const int p0 = t >> 5;
    const int j  = p0 & 1023;
    const int i0 = p0 >> 10;

    const int aj = asym[j];
    const int rj = resid[j];
    const int ej = ent[j];
    const int tj = tok[j];
    const int sj = sym[j];

    const f4 vE = Wv[130 * 32 + c4];           // entity row: reg for whole kernel

    size_t oidx = (size_t)t;

    // ---- PRIME: it = 0..3 with W from global (L1/L3-hot); stores start early ----
    #pragma unroll
    for (int it = 0; it < PRIME; ++it) {
        const int i  = i0 + 16 * it;
        const int ai = asym[i];
        const int ri = resid[i];
        const int ei = ent[i];
        const int ti = tok[i];
        const int si = sym[i];

        const bool sc = (ai == aj);
        const bool sr = (ri == rj);

        int dres = min(max(rj - ri + 32, 0), 64);
        int dtok = min(max(tj - ti + 32, 0), 64);
        int dch  = min(max(sj - si + 2, 0), 4);
        if (sc)        { dres = 64; dch = 4; }
        if (sc || sr)  { dtok = 64; }
        const float se = (ei == ej) ? 1.0f : 0.0f;

        const f4 v0 = Wv[dres * 32 + c4];
        const f4 v1 = Wv[(65 + dtok) * 32 + c4];
        const f4 v3 = Wv[(131 + dch) * 32 + c4];

        f4 r;
        r.x = fmaf(se, vE.x, v0.x + v1.x) + v3.x;
        r.y = fmaf(se, vE.y, v0.y + v1.y) + v3.y;
        r.z = fmaf(se, vE.z, v0.z + v1.z) + v3.z;
        r.w = fmaf(se, vE.w, v0.w + v1.w) + v3.w;

        outv[oidx] = r;
        oidx += (size_t)524288;
    }

    // ---- commit staged W to LDS, single sync ----
    #pragma unroll
    for (int k = 0; k < 8; ++k)
        sW[tid + k * 512] = st[k];
    if (tid < 256) sW[4096 + tid] = st8;
    __syncthreads();

    // ---- MAIN: it = 4..63 from LDS (identical math) ----
    #pragma unroll 4
    for (int it = PRIME; it < 64; ++it) {
        const int i  = i0 + 16 * it;
        const int ai = asym[i];
        const int ri = resid[i];
        const int ei = ent[i];
        const int ti = tok[i];
        const int si = sym[i];

        const bool sc = (ai == aj);
        const bool sr = (ri == rj);

        int dres = min(max(rj - ri + 32, 0), 64);
        int dtok = min(max(tj - ti + 32, 0), 64);
        int dch  = min(max(sj - si + 2, 0), 4);
        if (sc)        { dres = 64; dch = 4; }
        if (sc || sr)  { dtok = 64; }
        const float se = (ei == ej) ? 1.0f : 0.0f;

        const f4 v0 = sW[dres * 32 + c4];
        const f4 v1 = sW[(65 + dtok) * 32 + c4];
        const f4 v3 = sW[(131 + dch) * 32 + c4];

        f4 r;
        r.x = fmaf(se, vE.x, v0.x + v1.x) + v3.x;
        r.y = fmaf(se, vE.y, v0.y + v1.y) + v3.y;
        r.z = fmaf(se, vE.z, v0.z + v1.z) + v3.z;
        r.w = fmaf(se, vE.w, v0.w + v1.w) + v3.w;

        outv[oidx] = r;
        oidx += (size_t)524288;
    }
}

extern "C" void kernel_launch(void* const* d_in, const int* in_sizes, int n_in,
                              void* d_out, int out_size, void* d_ws, size_t ws_size,
                              hipStream_t stream) {
    const int*   asym  = (const int*)  d_in[0];
    const int*   resid = (const int*)  d_in[1];
    const int*   ent   = (const int*)  d_in[2];
    const int*   tok   = (const int*)  d_in[3];
    const int*   sym   = (const int*)  d_in[4];
    const float* W     = (const float*)d_in[5];
    f4* outv = (f4*)d_out;

    relpos_kernel<<<GRID, THREADS, 0, stream>>>(asym, resid, ent, tok, sym, W, outv);
}

// Round 10
// 105.715 us; speedup vs baseline: 13.8913x; 1.0646x over previous
//
#include <hip/hip_runtime.h>

// RelativePositionEncoding — out 512 MiB fp32, HBM-write-bound.
// R10: R9 structure (prime-overlap staging, proven -3.4us) with GRID halved
// 1024->512: staging HBM traffic 71->36 MB, same 16 waves/CU (2 blocks/CU,
// LDS 2x69.6KB=139KB), per-thread iterations 64->128.
// Decomposition of R9's 112.5us: ~78 steady write (6.9 TB/s, R7/R8-proven)
// + ~14-25 launch transient (store-only pays it too, R5) + ~10-20 staging
// fetch/cohort residual <- this round's target.

typedef float f4 __attribute__((ext_vector_type(4)));

constexpr int ROWS = 136;      // 65 rel_pos | 65 rel_token | 1 entity | 5 rel_chain
constexpr int THREADS = 512;
constexpr int GRID = 512;      // 262,144 threads x 128 f4 stores
constexpr int ITERS = 128;
constexpr int PRIME = 4;       // iterations served from global W before LDS commit

__global__ __launch_bounds__(THREADS)
void relpos_kernel(const int* __restrict__ asym,
                   const int* __restrict__ resid,
                   const int* __restrict__ ent,
                   const int* __restrict__ tok,
                   const int* __restrict__ sym,
                   const float* __restrict__ W,
                   f4* __restrict__ outv)
{
    __shared__ f4 sW[ROWS * 32];               // 69,632 B
    const int tid = threadIdx.x;
    const f4* Wv = reinterpret_cast<const f4*>(W);   // W as [136*32] f4

    // ---- issue W->reg staging loads NOW; they fly under the prime phase ----
    f4 st[8];                                  // 4096 of 4352 f4
    #pragma unroll
    for (int k = 0; k < 8; ++k)
        st[k] = Wv[tid + k * 512];
    f4 st8;                                    // remaining 256 f4
    if (tid < 256) st8 = Wv[4096 + tid];

    // ---- decomposition: c4 fixed, j fixed, i = i0 + 8*it (i0 block-uniform) ----
    const int t  = blockIdx.x * THREADS + tid;
    const int c4 = t & 31;
    const int p0 = t >> 5;
    const int j  = p0 & 1023;
    const int i0 = p0 >> 10;                   // in [0,8)

    const int aj = asym[j];
    const int rj = resid[j];
    const int ej = ent[j];
    const int tj = tok[j];
    const int sj = sym[j];

    const f4 vE = Wv[130 * 32 + c4];           // entity row: reg for whole kernel

    size_t oidx = (size_t)t;

    // ---- PRIME: it = 0..3 with W from global (L1/L2-hot); stores start early ----
    #pragma unroll
    for (int it = 0; it < PRIME; ++it) {
        const int i  = i0 + 8 * it;
        const int ai = asym[i];
        const int ri = resid[i];
        const int ei = ent[i];
        const int ti = tok[i];
        const int si = sym[i];

        const bool sc = (ai == aj);
        const bool sr = (ri == rj);

        int dres = min(max(rj - ri + 32, 0), 64);
        int dtok = min(max(tj - ti + 32, 0), 64);
        int dch  = min(max(sj - si + 2, 0), 4);
        if (sc)        { dres = 64; dch = 4; }
        if (sc || sr)  { dtok = 64; }
        const float se = (ei == ej) ? 1.0f : 0.0f;

        const f4 v0 = Wv[dres * 32 + c4];
        const f4 v1 = Wv[(65 + dtok) * 32 + c4];
        const f4 v3 = Wv[(131 + dch) * 32 + c4];

        f4 r;
        r.x = fmaf(se, vE.x, v0.x + v1.x) + v3.x;
        r.y = fmaf(se, vE.y, v0.y + v1.y) + v3.y;
        r.z = fmaf(se, vE.z, v0.z + v1.z) + v3.z;
        r.w = fmaf(se, vE.w, v0.w + v1.w) + v3.w;

        outv[oidx] = r;
        oidx += (size_t)GRID * THREADS;        // 262,144 f4 = 4 MiB
    }

    // ---- commit staged W to LDS, single sync ----
    #pragma unroll
    for (int k = 0; k < 8; ++k)
        sW[tid + k * 512] = st[k];
    if (tid < 256) sW[4096 + tid] = st8;
    __syncthreads();

    // ---- MAIN: it = 4..127 from LDS (identical math) ----
    #pragma unroll 4
    for (int it = PRIME; it < ITERS; ++it) {
        const int i  = i0 + 8 * it;
        const int ai = asym[i];
        const int ri = resid[i];
        const int ei = ent[i];
        const int ti = tok[i];
        const int si = sym[i];

        const bool sc = (ai == aj);
        const bool sr = (ri == rj);

        int dres = min(max(rj - ri + 32, 0), 64);
        int dtok = min(max(tj - ti + 32, 0), 64);
        int dch  = min(max(sj - si + 2, 0), 4);
        if (sc)        { dres = 64; dch = 4; }
        if (sc || sr)  { dtok = 64; }
        const float se = (ei == ej) ? 1.0f : 0.0f;

        const f4 v0 = sW[dres * 32 + c4];
        const f4 v1 = sW[(65 + dtok) * 32 + c4];
        const f4 v3 = sW[(131 + dch) * 32 + c4];

        f4 r;
        r.x = fmaf(se, vE.x, v0.x + v1.x) + v3.x;
        r.y = fmaf(se, vE.y, v0.y + v1.y) + v3.y;
        r.z = fmaf(se, vE.z, v0.z + v1.z) + v3.z;
        r.w = fmaf(se, vE.w, v0.w + v1.w) + v3.w;

        outv[oidx] = r;
        oidx += (size_t)GRID * THREADS;
    }
}

extern "C" void kernel_launch(void* const* d_in, const int* in_sizes, int n_in,
                              void* d_out, int out_size, void* d_ws, size_t ws_size,
                              hipStream_t stream) {
    const int*   asym  = (const int*)  d_in[0];
    const int*   resid = (const int*)  d_in[1];
    const int*   ent   = (const int*)  d_in[2];
    const int*   tok   = (const int*)  d_in[3];
    const int*   sym   = (const int*)  d_in[4];
    const float* W     = (const float*)d_in[5];
    f4* outv = (f4*)d_out;

    relpos_kernel<<<GRID, THREADS, 0, stream>>>(asym, resid, ent, tok, sym, W, outv);
}

// Round 11
// 105.537 us; speedup vs baseline: 13.9148x; 1.0017x over previous
//
#include <hip/hip_runtime.h>

// RelativePositionEncoding — out 512 MiB fp32, HBM-write-bound.
// R11: R10 structure + one more staging halving WITHOUT occupancy loss:
// GRID 512x512thr -> 256x1024thr. Same 262,144 threads, same mapping, same
// 16 waves/CU — but 1 block/CU (single staging cohort, no tail) and W fetch
// traffic 36 -> 17.8 MB. Ladder: R9 112.5 -> R10 105.7 (staging halved) ->
// predict 101-104 here. Budget: ~78us steady write + launch ramp.

typedef float f4 __attribute__((ext_vector_type(4)));

constexpr int ROWS = 136;      // 65 rel_pos | 65 rel_token | 1 entity | 5 rel_chain
constexpr int THREADS = 1024;
constexpr int GRID = 256;      // 262,144 threads x 128 f4 stores
constexpr int ITERS = 128;
constexpr int PRIME = 4;       // iterations served from global W before LDS commit

__global__ __launch_bounds__(THREADS)
void relpos_kernel(const int* __restrict__ asym,
                   const int* __restrict__ resid,
                   const int* __restrict__ ent,
                   const int* __restrict__ tok,
                   const int* __restrict__ sym,
                   const float* __restrict__ W,
                   f4* __restrict__ outv)
{
    __shared__ f4 sW[ROWS * 32];               // 69,632 B, 1 block/CU
    const int tid = threadIdx.x;
    const f4* Wv = reinterpret_cast<const f4*>(W);   // W as [136*32] f4

    // ---- issue W->reg staging loads NOW; they fly under the prime phase ----
    f4 st[4];                                  // 4096 of 4352 f4
    #pragma unroll
    for (int k = 0; k < 4; ++k)
        st[k] = Wv[tid + k * 1024];
    f4 st8;                                    // remaining 256 f4
    if (tid < 256) st8 = Wv[4096 + tid];

    // ---- decomposition: c4 fixed, j fixed, i = i0 + 8*it (i0 block-uniform-ish) ----
    const int t  = blockIdx.x * THREADS + tid;
    const int c4 = t & 31;
    const int p0 = t >> 5;
    const int j  = p0 & 1023;
    const int i0 = p0 >> 10;                   // in [0,8)

    const int aj = asym[j];
    const int rj = resid[j];
    const int ej = ent[j];
    const int tj = tok[j];
    const int sj = sym[j];

    const f4 vE = Wv[130 * 32 + c4];           // entity row: reg for whole kernel

    size_t oidx = (size_t)t;

    // ---- PRIME: it = 0..3 with W from global (L1/L2-hot); stores start early ----
    #pragma unroll
    for (int it = 0; it < PRIME; ++it) {
        const int i  = i0 + 8 * it;
        const int ai = asym[i];
        const int ri = resid[i];
        const int ei = ent[i];
        const int ti = tok[i];
        const int si = sym[i];

        const bool sc = (ai == aj);
        const bool sr = (ri == rj);

        int dres = min(max(rj - ri + 32, 0), 64);
        int dtok = min(max(tj - ti + 32, 0), 64);
        int dch  = min(max(sj - si + 2, 0), 4);
        if (sc)        { dres = 64; dch = 4; }
        if (sc || sr)  { dtok = 64; }
        const float se = (ei == ej) ? 1.0f : 0.0f;

        const f4 v0 = Wv[dres * 32 + c4];
        const f4 v1 = Wv[(65 + dtok) * 32 + c4];
        const f4 v3 = Wv[(131 + dch) * 32 + c4];

        f4 r;
        r.x = fmaf(se, vE.x, v0.x + v1.x) + v3.x;
        r.y = fmaf(se, vE.y, v0.y + v1.y) + v3.y;
        r.z = fmaf(se, vE.z, v0.z + v1.z) + v3.z;
        r.w = fmaf(se, vE.w, v0.w + v1.w) + v3.w;

        outv[oidx] = r;
        oidx += (size_t)GRID * THREADS;        // 262,144 f4 = 4 MiB
    }

    // ---- commit staged W to LDS, single sync ----
    #pragma unroll
    for (int k = 0; k < 4; ++k)
        sW[tid + k * 1024] = st[k];
    if (tid < 256) sW[4096 + tid] = st8;
    __syncthreads();

    // ---- MAIN: it = 4..127 from LDS (identical math) ----
    #pragma unroll 4
    for (int it = PRIME; it < ITERS; ++it) {
        const int i  = i0 + 8 * it;
        const int ai = asym[i];
        const int ri = resid[i];
        const int ei = ent[i];
        const int ti = tok[i];
        const int si = sym[i];

        const bool sc = (ai == aj);
        const bool sr = (ri == rj);

        int dres = min(max(rj - ri + 32, 0), 64);
        int dtok = min(max(tj - ti + 32, 0), 64);
        int dch  = min(max(sj - si + 2, 0), 4);
        if (sc)        { dres = 64; dch = 4; }
        if (sc || sr)  { dtok = 64; }
        const float se = (ei == ej) ? 1.0f : 0.0f;

        const f4 v0 = sW[dres * 32 + c4];
        const f4 v1 = sW[(65 + dtok) * 32 + c4];
        const f4 v3 = sW[(131 + dch) * 32 + c4];

        f4 r;
        r.x = fmaf(se, vE.x, v0.x + v1.x) + v3.x;
        r.y = fmaf(se, vE.y, v0.y + v1.y) + v3.y;
        r.z = fmaf(se, vE.z, v0.z + v1.z) + v3.z;
        r.w = fmaf(se, vE.w, v0.w + v1.w) + v3.w;

        outv[oidx] = r;
        oidx += (size_t)GRID * THREADS;
    }
}

extern "C" void kernel_launch(void* const* d_in, const int* in_sizes, int n_in,
                              void* d_out, int out_size, void* d_ws, size_t ws_size,
                              hipStream_t stream) {
    const int*   asym  = (const int*)  d_in[0];
    const int*   resid = (const int*)  d_in[1];
    const int*   ent   = (const int*)  d_in[2];
    const int*   tok   = (const int*)  d_in[3];
    const int*   sym   = (const int*)  d_in[4];
    const float* W     = (const float*)d_in[5];
    f4* outv = (f4*)d_out;

    relpos_kernel<<<GRID, THREADS, 0, stream>>>(asym, resid, ent, tok, sym, W, outv);
}